// Round 1
// 198.646 us; speedup vs baseline: 1.0191x; 1.0191x over previous
//
#include <hip/hip_runtime.h>
#include <cstddef>

// ---------------------------------------------------------------------------
// GCN forward: 3 x ( h@W bf16 MFMA -> packed-bf16 xw -> CSR segsum+LN(+ReLU) )
// N=50000, E=800000, D: 128 -> 128 -> 128 -> 64.
// R14 = R13 + agg/gemm FUSION at both layer boundaries:
//  - agg_gemm<NCOLS_OUT>: block = 16-node tile (4 waves x 4 nodes). Gather +
//    LN + ReLU exactly as R12/R13, but the A-fragment-ordered 16x128 tile goes
//    to LDS (4KB) instead of global. After __syncthreads each wave runs the
//    verified MFMA + packed-C epilogue for its column slice (32 or 16 cols).
//  - Removes the hb round-trip (2 x 12.8MB write + 2 x 12.8MB read) and two
//    dispatches (7 -> 5). xw buffers ping-pong instead.
//  - gemm0 (fp32 feat A-path) and final agg_ln64 unchanged.
// ---------------------------------------------------------------------------

typedef __attribute__((ext_vector_type(8))) short bf16x8;
typedef __attribute__((ext_vector_type(4))) float floatx4;
typedef __attribute__((ext_vector_type(4))) unsigned int uintx4;
typedef __attribute__((ext_vector_type(2))) unsigned int uintx2;

static __device__ __forceinline__ unsigned int f2bf(float f) {
    union { float f; unsigned int u; } v; v.f = f;
    unsigned int u = v.u;
    u += 0x7fffu + ((u >> 16) & 1u);
    return u >> 16;
}
static __device__ __forceinline__ float bf_lo(unsigned int p) {
    union { unsigned int u; float f; } v; v.u = p << 16; return v.f;
}
static __device__ __forceinline__ float bf_hi(unsigned int p) {
    union { unsigned int u; float f; } v; v.u = p & 0xffff0000u; return v.f;
}
static __device__ __forceinline__ void acc8(float* a, uintx4 v) {
    a[0] += bf_lo(v.x); a[1] += bf_hi(v.x);
    a[2] += bf_lo(v.y); a[3] += bf_hi(v.y);
    a[4] += bf_lo(v.z); a[5] += bf_hi(v.z);
    a[6] += bf_lo(v.w); a[7] += bf_hi(v.w);
}
static __device__ __forceinline__ void acc4(float* a, uintx2 v) {
    a[0] += bf_lo(v.x); a[1] += bf_hi(v.x);
    a[2] += bf_lo(v.y); a[3] += bf_hi(v.y);
}

// ---- W[k][n] fp32 -> FRAGMENT-ORDERED WtF, 3 matrices ----------------------
// Layout: uint idx = t*1024 + s*256 + lane*4 + j  (t = 16-col tile, s = k0/32,
// lane = quad*16+mcol). Holds packed bf16 pair W[k][n],W[k+1][n] with
// n = t*16+mcol, k = s*32+quad*8+2j. B-load in gemm = lane-contiguous uintx4.
__global__ __launch_bounds__(256) void cvt_w(const float* __restrict__ W0,
                                             const float* __restrict__ W1,
                                             const float* __restrict__ W2,
                                             unsigned int* __restrict__ WtF) {
    const int m = blockIdx.x >> 4;
    const int slice = blockIdx.x & 15;
    const float* W = (m == 0) ? W0 : (m == 1) ? W1 : W2;
    const int ncols = (m == 2) ? 64 : 128;
    unsigned int* dst = WtF + m * 128 * 64;
    const int total = ncols * 64;                  // uints
    for (int idx = slice * 256 + threadIdx.x; idx < total; idx += 16 * 256) {
        const int j    = idx & 3;
        const int lane = (idx >> 2) & 63;
        const int s    = (idx >> 8) & 3;
        const int t    = idx >> 10;
        const int mcol = lane & 15;
        const int quad = lane >> 4;
        const int n = t * 16 + mcol;
        const int k = s * 32 + quad * 8 + 2 * j;
        unsigned int lo = f2bf(W[(size_t)k * ncols + n]);
        unsigned int hi = f2bf(W[(size_t)(k + 1) * ncols + n]);
        dst[idx] = (hi << 16) | lo;
    }
}

// ---- bf16 MFMA GEMM, 1 wave per block (16 rows x NCOLS) --------------------
// Layer 0 only now: A fp32 row-major (feat), in-register bf16 convert.
template <int NCOLS, bool A_FP32>
__global__ __launch_bounds__(64) void gemm_mfma(const void* __restrict__ Av,
                                                const unsigned int* __restrict__ Wt,
                                                unsigned int* __restrict__ C,
                                                int M) {
    const int lane = threadIdx.x;
    const int row0 = blockIdx.x * 16;
    const int quad = lane >> 4;
    const int mcol = lane & 15;

    constexpr int NT = NCOLS / 16;
    floatx4 acc[NT];
    #pragma unroll
    for (int t = 0; t < NT; ++t) acc[t] = (floatx4){0.f, 0.f, 0.f, 0.f};

    int aidx = row0 + mcol; if (aidx >= M) aidx = M - 1;
    const float*        arowF = (const float*)Av + (size_t)aidx * 128 + quad * 8;
    const unsigned int* afrag = (const unsigned int*)Av + (size_t)blockIdx.x * 1024 + lane * 4;
    const unsigned int* bbase = Wt + lane * 4;

    #pragma unroll
    for (int s = 0; s < 4; ++s) {
        bf16x8 a;
        if constexpr (A_FP32) {
            float4 fa = *(const float4*)(arowF + s * 32);
            float4 fb = *(const float4*)(arowF + s * 32 + 4);
            uintx4 ap;
            ap.x = (f2bf(fa.y) << 16) | f2bf(fa.x);
            ap.y = (f2bf(fa.w) << 16) | f2bf(fa.z);
            ap.z = (f2bf(fb.y) << 16) | f2bf(fb.x);
            ap.w = (f2bf(fb.w) << 16) | f2bf(fb.z);
            a = __builtin_bit_cast(bf16x8, ap);
        } else {
            uintx4 ap = *(const uintx4*)(afrag + s * 256);
            a = __builtin_bit_cast(bf16x8, ap);
        }
        #pragma unroll
        for (int t = 0; t < NT; ++t) {
            uintx4 bp = *(const uintx4*)(bbase + t * 1024 + s * 256);
            bf16x8 b = __builtin_bit_cast(bf16x8, bp);
            acc[t] = __builtin_amdgcn_mfma_f32_16x16x32_bf16(a, b, acc[t], 0, 0, 0);
        }
    }

    // C/D layout: col = lane&15, row = quad*4 + reg  [m89/m91]; row-major out.
    const int rowStride = NCOLS >> 1;
    #pragma unroll
    for (int t = 0; t < NT; ++t) {
        #pragma unroll
        for (int r = 0; r < 4; ++r) {
            unsigned int mybf = f2bf(acc[t][r]);
            unsigned int pair = __shfl_xor(mybf, 1, 64);
            int orow = row0 + quad * 4 + r;
            if (orow < M && (mcol & 1) == 0) {
                unsigned int packed = (pair << 16) | mybf;
                C[(size_t)orow * rowStride + t * 8 + (mcol >> 1)] = packed;
            }
        }
    }
}

// ---- FUSED: CSR segsum + LN + ReLU (D=128) -> LDS A-tile -> MFMA x W -------
// Block = 16-node tile, 256 threads = 4 waves. Wave w aggregates nodes
// tile*16 + w*4 + n (n=0..3), writes LN'd rows into LDS in A-fragment order
// (uint idx = (sl>>2)*256 + (sl&3)*64 + m*4 — identical to the R13 global
// layout the MFMA consumed). After barrier, wave w computes cols
// [w*NCOLS_OUT/4, ...) of the 16 x NCOLS_OUT GEMM and writes packed-bf16
// row-major C (consumed by the next gather).
template <int NCOLS_OUT>
__global__ __launch_bounds__(256) void agg_gemm(const unsigned int* __restrict__ xw,
                                                const int* __restrict__ ptr,
                                                const int* __restrict__ col,
                                                const unsigned int* __restrict__ Wt,
                                                unsigned int* __restrict__ C,
                                                int N) {
    __shared__ unsigned int lds[1024];           // 16 rows x 128 bf16, A-frag order
    const int tile = blockIdx.x;
    const int wave = threadIdx.x >> 6;
    const int lane = threadIdx.x & 63;
    const int g  = lane >> 4;     // 0..3 edge group
    const int sl = lane & 15;     // 0..15 sublane (owns 8 features)

    // ---- phase 1: aggregate + LN + ReLU, 4 nodes per wave ----
    const unsigned int* base = xw + sl * 4;
    #pragma unroll
    for (int n = 0; n < 4; ++n) {
        const int m = wave * 4 + n;
        const int node = tile * 16 + m;
        const int nodeC = node < N ? node : N - 1;
        const int s = ptr[nodeC];
        const int e = node < N ? ptr[nodeC + 1] : s;

        float accA[8] = {}, accB[8] = {};
        int i = s + g;
        for (; i + 12 < e; i += 16) {
            uintx4 v0 = *(const uintx4*)(base + (size_t)col[i]      * 64);
            uintx4 v1 = *(const uintx4*)(base + (size_t)col[i + 4]  * 64);
            uintx4 v2 = *(const uintx4*)(base + (size_t)col[i + 8]  * 64);
            uintx4 v3 = *(const uintx4*)(base + (size_t)col[i + 12] * 64);
            acc8(accA, v0); acc8(accB, v1); acc8(accA, v2); acc8(accB, v3);
        }
        for (; i < e; i += 4) {
            uintx4 v0 = *(const uintx4*)(base + (size_t)col[i] * 64);
            acc8(accA, v0);
        }

        float acc[8];
        #pragma unroll
        for (int j = 0; j < 8; ++j) acc[j] = accA[j] + accB[j];

        #pragma unroll
        for (int j = 0; j < 8; ++j) {
            acc[j] += __shfl_xor(acc[j], 16, 64);
            acc[j] += __shfl_xor(acc[j], 32, 64);
        }
        float s1 = 0.f, s2 = 0.f;
        #pragma unroll
        for (int j = 0; j < 8; ++j) { s1 += acc[j]; s2 += acc[j] * acc[j]; }
        #pragma unroll
        for (int mm = 8; mm >= 1; mm >>= 1) {
            s1 += __shfl_xor(s1, mm, 64);
            s2 += __shfl_xor(s2, mm, 64);
        }
        const float mean = s1 * (1.0f / 128.0f);
        const float var  = s2 * (1.0f / 128.0f) - mean * mean;
        const float inv  = rsqrtf(var + 1e-5f);

        if (g == 0) {
            float o[8];
            #pragma unroll
            for (int j = 0; j < 8; ++j)
                o[j] = fmaxf((acc[j] - mean) * inv, 0.f);
            uintx4 p;
            p.x = (f2bf(o[1]) << 16) | f2bf(o[0]);
            p.y = (f2bf(o[3]) << 16) | f2bf(o[2]);
            p.z = (f2bf(o[5]) << 16) | f2bf(o[4]);
            p.w = (f2bf(o[7]) << 16) | f2bf(o[6]);
            *(uintx4*)(lds + (sl >> 2) * 256 + (sl & 3) * 64 + m * 4) = p;
        }
    }
    __syncthreads();

    // ---- phase 2: 16 x NCOLS_OUT MFMA, wave covers NCOLS_OUT/4 cols --------
    constexpr int WT = NCOLS_OUT / 64;           // tiles per wave (2 or 1)
    const int quad = lane >> 4;
    const int mcol = lane & 15;
    floatx4 acc[WT];
    #pragma unroll
    for (int t = 0; t < WT; ++t) acc[t] = (floatx4){0.f, 0.f, 0.f, 0.f};

    const unsigned int* bbase = Wt + lane * 4;
    #pragma unroll
    for (int s4 = 0; s4 < 4; ++s4) {
        uintx4 ap = *(const uintx4*)(lds + s4 * 256 + lane * 4);
        bf16x8 a = __builtin_bit_cast(bf16x8, ap);
        #pragma unroll
        for (int tt = 0; tt < WT; ++tt) {
            const int t = wave * WT + tt;
            uintx4 bp = *(const uintx4*)(bbase + t * 1024 + s4 * 256);
            bf16x8 b = __builtin_bit_cast(bf16x8, bp);
            acc[tt] = __builtin_amdgcn_mfma_f32_16x16x32_bf16(a, b, acc[tt], 0, 0, 0);
        }
    }

    const int rowStride = NCOLS_OUT >> 1;
    #pragma unroll
    for (int tt = 0; tt < WT; ++tt) {
        const int t = wave * WT + tt;
        #pragma unroll
        for (int r = 0; r < 4; ++r) {
            unsigned int mybf = f2bf(acc[tt][r]);
            unsigned int pair = __shfl_xor(mybf, 1, 64);
            const int orow = tile * 16 + quad * 4 + r;
            if (orow < N && (mcol & 1) == 0) {
                unsigned int packed = (pair << 16) | mybf;
                C[(size_t)orow * rowStride + t * 8 + (mcol >> 1)] = packed;
            }
        }
    }
}

// ---- fused CSR segsum + LN, D=64, fp32 out, no ReLU (final layer) ----------
__global__ __launch_bounds__(256) void agg_ln64(const unsigned int* __restrict__ xw,
                                                const int* __restrict__ ptr,
                                                const int* __restrict__ col,
                                                float* __restrict__ out, int N) {
    const int node = blockIdx.x * 4 + (threadIdx.x >> 6);
    if (node >= N) return;
    const int lane = threadIdx.x & 63;
    const int g  = lane >> 4;     // 0..3 edge group
    const int sl = lane & 15;     // 0..15 sublane (owns 4 features)
    const int s = ptr[node];
    const int e = ptr[node + 1];

    float accA[4] = {}, accB[4] = {};
    const unsigned int* base = xw + sl * 2;
    int i = s + g;
    for (; i + 12 < e; i += 16) {
        uintx2 v0 = *(const uintx2*)(base + (size_t)col[i]      * 32);
        uintx2 v1 = *(const uintx2*)(base + (size_t)col[i + 4]  * 32);
        uintx2 v2 = *(const uintx2*)(base + (size_t)col[i + 8]  * 32);
        uintx2 v3 = *(const uintx2*)(base + (size_t)col[i + 12] * 32);
        acc4(accA, v0); acc4(accB, v1); acc4(accA, v2); acc4(accB, v3);
    }
    for (; i < e; i += 4) {
        uintx2 v0 = *(const uintx2*)(base + (size_t)col[i] * 32);
        acc4(accA, v0);
    }

    float acc[4];
    #pragma unroll
    for (int j = 0; j < 4; ++j) acc[j] = accA[j] + accB[j];

    #pragma unroll
    for (int j = 0; j < 4; ++j) {
        acc[j] += __shfl_xor(acc[j], 16, 64);
        acc[j] += __shfl_xor(acc[j], 32, 64);
    }
    float s1 = 0.f, s2 = 0.f;
    #pragma unroll
    for (int j = 0; j < 4; ++j) { s1 += acc[j]; s2 += acc[j] * acc[j]; }
    #pragma unroll
    for (int m = 8; m >= 1; m >>= 1) {
        s1 += __shfl_xor(s1, m, 64);
        s2 += __shfl_xor(s2, m, 64);
    }
    const float mean = s1 * (1.0f / 64.0f);
    const float var  = s2 * (1.0f / 64.0f) - mean * mean;
    const float inv  = rsqrtf(var + 1e-5f);

    if (g == 0) {
        float4 o;
        o.x = (acc[0] - mean) * inv;
        o.y = (acc[1] - mean) * inv;
        o.z = (acc[2] - mean) * inv;
        o.w = (acc[3] - mean) * inv;
        *(float4*)(out + (size_t)node * 64 + sl * 4) = o;
    }
}

extern "C" void kernel_launch(void* const* d_in, const int* in_sizes, int n_in,
                              void* d_out, int out_size, void* d_ws, size_t ws_size,
                              hipStream_t stream) {
    const float* feat = (const float*)d_in[0];   // [N,128]
    const float* W0   = (const float*)d_in[1];   // [128,128]
    const float* W1   = (const float*)d_in[2];   // [128,128]
    const float* W2   = (const float*)d_in[3];   // [128,64]
    const int*   ptr  = (const int*)d_in[4];     // [N+1]
    const int*   col  = (const int*)d_in[5];     // [E]
    // d_in[6] = edge_rows, unused (CSR ptr encodes the same segments)

    const int N = in_sizes[4] - 1;               // 50000 (= 3125 * 16)

    unsigned int* buf0 = (unsigned int*)d_ws;                // [N,64] uint, row-major packed
    unsigned int* buf1 = buf0 + (size_t)N * 64;              // [N,64] uint, row-major packed
    unsigned int* WtP  = buf1 + (size_t)N * 64;              // 3 x frag-ordered W
    float*        out  = (float*)d_out;                      // [N,64]

    const int gemmBlocks = (N + 15) / 16;        // 3125 (16-node tiles)
    const int nodeBlocks = (N + 3) / 4;          // 12500

    cvt_w<<<48, 256, 0, stream>>>(W0, W1, W2, WtP);

    // Layer 0 GEMM (fp32 feat A-path, in-register convert)
    gemm_mfma<128, true><<<gemmBlocks, 64, 0, stream>>>(feat, WtP, buf0, N);
    // Layer 0 agg + LN + ReLU fused with layer 1 GEMM
    agg_gemm<128><<<gemmBlocks, 256, 0, stream>>>(buf0, ptr, col, WtP + 128 * 64, buf1, N);
    // Layer 1 agg + LN + ReLU fused with layer 2 GEMM (D_out=64)
    agg_gemm<64><<<gemmBlocks, 256, 0, stream>>>(buf1, ptr, col, WtP + 2 * 128 * 64, buf0, N);
    // Layer 2 agg + LN (no ReLU), fp32 out
    agg_ln64<<<nodeBlocks, 256, 0, stream>>>(buf0, ptr, col, out, N);
}

// Round 2
// 188.959 us; speedup vs baseline: 1.0714x; 1.0513x over previous
//
#include <hip/hip_runtime.h>
#include <cstddef>

// ---------------------------------------------------------------------------
// GCN forward: 3 x ( h@W bf16 MFMA -> packed-bf16 xw -> CSR segsum+LN(+ReLU) )
// N=50000, E=800000, D: 128 -> 128 -> 128 -> 64.
// R15 = R14 + LATENCY-PIPELINED GATHER (the 48us agg kernels were latency-
// bound: MfmaUtil 1%, VALU 41%, HBM 23%):
//  - Each wave walks its 4 nodes' edge lists CONCURRENTLY (acc[4][8]), one
//    predicated loop over maxlen -- no serial per-node remainder chains.
//  - Explicit 2-deep pipeline: col indices prefetched 2 stages ahead,
//    gathers ping-pong double-buffered (8 gathers + 8 col loads in flight).
//  - OOB lanes: index clamped to a valid edge, accumulate predicated off.
//  - Same restructure for final agg_ln64 (4 nodes/wave, 16 nodes/block).
// ---------------------------------------------------------------------------

typedef __attribute__((ext_vector_type(8))) short bf16x8;
typedef __attribute__((ext_vector_type(4))) float floatx4;
typedef __attribute__((ext_vector_type(4))) unsigned int uintx4;
typedef __attribute__((ext_vector_type(2))) unsigned int uintx2;

static __device__ __forceinline__ unsigned int f2bf(float f) {
    union { float f; unsigned int u; } v; v.f = f;
    unsigned int u = v.u;
    u += 0x7fffu + ((u >> 16) & 1u);
    return u >> 16;
}
static __device__ __forceinline__ float bf_lo(unsigned int p) {
    union { unsigned int u; float f; } v; v.u = p << 16; return v.f;
}
static __device__ __forceinline__ float bf_hi(unsigned int p) {
    union { unsigned int u; float f; } v; v.u = p & 0xffff0000u; return v.f;
}
static __device__ __forceinline__ void acc8(float* a, uintx4 v) {
    a[0] += bf_lo(v.x); a[1] += bf_hi(v.x);
    a[2] += bf_lo(v.y); a[3] += bf_hi(v.y);
    a[4] += bf_lo(v.z); a[5] += bf_hi(v.z);
    a[6] += bf_lo(v.w); a[7] += bf_hi(v.w);
}
static __device__ __forceinline__ void acc4(float* a, uintx2 v) {
    a[0] += bf_lo(v.x); a[1] += bf_hi(v.x);
    a[2] += bf_lo(v.y); a[3] += bf_hi(v.y);
}

// ---- W[k][n] fp32 -> FRAGMENT-ORDERED WtF, 3 matrices ----------------------
__global__ __launch_bounds__(256) void cvt_w(const float* __restrict__ W0,
                                             const float* __restrict__ W1,
                                             const float* __restrict__ W2,
                                             unsigned int* __restrict__ WtF) {
    const int m = blockIdx.x >> 4;
    const int slice = blockIdx.x & 15;
    const float* W = (m == 0) ? W0 : (m == 1) ? W1 : W2;
    const int ncols = (m == 2) ? 64 : 128;
    unsigned int* dst = WtF + m * 128 * 64;
    const int total = ncols * 64;                  // uints
    for (int idx = slice * 256 + threadIdx.x; idx < total; idx += 16 * 256) {
        const int j    = idx & 3;
        const int lane = (idx >> 2) & 63;
        const int s    = (idx >> 8) & 3;
        const int t    = idx >> 10;
        const int mcol = lane & 15;
        const int quad = lane >> 4;
        const int n = t * 16 + mcol;
        const int k = s * 32 + quad * 8 + 2 * j;
        unsigned int lo = f2bf(W[(size_t)k * ncols + n]);
        unsigned int hi = f2bf(W[(size_t)(k + 1) * ncols + n]);
        dst[idx] = (hi << 16) | lo;
    }
}

// ---- bf16 MFMA GEMM, 1 wave per block (16 rows x NCOLS) --------------------
// Layer 0 only: A fp32 row-major (feat), in-register bf16 convert.
template <int NCOLS, bool A_FP32>
__global__ __launch_bounds__(64) void gemm_mfma(const void* __restrict__ Av,
                                                const unsigned int* __restrict__ Wt,
                                                unsigned int* __restrict__ C,
                                                int M) {
    const int lane = threadIdx.x;
    const int row0 = blockIdx.x * 16;
    const int quad = lane >> 4;
    const int mcol = lane & 15;

    constexpr int NT = NCOLS / 16;
    floatx4 acc[NT];
    #pragma unroll
    for (int t = 0; t < NT; ++t) acc[t] = (floatx4){0.f, 0.f, 0.f, 0.f};

    int aidx = row0 + mcol; if (aidx >= M) aidx = M - 1;
    const float*        arowF = (const float*)Av + (size_t)aidx * 128 + quad * 8;
    const unsigned int* afrag = (const unsigned int*)Av + (size_t)blockIdx.x * 1024 + lane * 4;
    const unsigned int* bbase = Wt + lane * 4;

    #pragma unroll
    for (int s = 0; s < 4; ++s) {
        bf16x8 a;
        if constexpr (A_FP32) {
            float4 fa = *(const float4*)(arowF + s * 32);
            float4 fb = *(const float4*)(arowF + s * 32 + 4);
            uintx4 ap;
            ap.x = (f2bf(fa.y) << 16) | f2bf(fa.x);
            ap.y = (f2bf(fa.w) << 16) | f2bf(fa.z);
            ap.z = (f2bf(fb.y) << 16) | f2bf(fb.x);
            ap.w = (f2bf(fb.w) << 16) | f2bf(fb.z);
            a = __builtin_bit_cast(bf16x8, ap);
        } else {
            uintx4 ap = *(const uintx4*)(afrag + s * 256);
            a = __builtin_bit_cast(bf16x8, ap);
        }
        #pragma unroll
        for (int t = 0; t < NT; ++t) {
            uintx4 bp = *(const uintx4*)(bbase + t * 1024 + s * 256);
            bf16x8 b = __builtin_bit_cast(bf16x8, bp);
            acc[t] = __builtin_amdgcn_mfma_f32_16x16x32_bf16(a, b, acc[t], 0, 0, 0);
        }
    }

    const int rowStride = NCOLS >> 1;
    #pragma unroll
    for (int t = 0; t < NT; ++t) {
        #pragma unroll
        for (int r = 0; r < 4; ++r) {
            unsigned int mybf = f2bf(acc[t][r]);
            unsigned int pair = __shfl_xor(mybf, 1, 64);
            int orow = row0 + quad * 4 + r;
            if (orow < M && (mcol & 1) == 0) {
                unsigned int packed = (pair << 16) | mybf;
                C[(size_t)orow * rowStride + t * 8 + (mcol >> 1)] = packed;
            }
        }
    }
}

// ---- FUSED: CSR segsum + LN + ReLU (D=128) -> LDS A-tile -> MFMA x W -------
// Block = 16-node tile, 4 waves x 4 nodes. Wave walks its 4 nodes' edges
// CONCURRENTLY with a 2-deep software pipeline (col prefetch 2 ahead, gather
// ping-pong). Then LN+ReLU per node, LDS A-frag tile, barrier, MFMA slice.
template <int NCOLS_OUT>
__global__ __launch_bounds__(256) void agg_gemm(const unsigned int* __restrict__ xw,
                                                const int* __restrict__ ptr,
                                                const int* __restrict__ col,
                                                const unsigned int* __restrict__ Wt,
                                                unsigned int* __restrict__ C,
                                                int N, int Emax /* = E-1 */) {
    __shared__ unsigned int lds[1024];           // 16 rows x 128 bf16, A-frag order
    const int tile = blockIdx.x;
    const int wave = threadIdx.x >> 6;
    const int lane = threadIdx.x & 63;
    const int g  = lane >> 4;     // 0..3 edge group
    const int sl = lane & 15;     // 0..15 sublane (owns 8 features)

    // ---- phase 1: pipelined concurrent gather for 4 nodes ----
    int s0[4], len[4];
    int maxlen = 0;
    #pragma unroll
    for (int n = 0; n < 4; ++n) {
        const int node = tile * 16 + wave * 4 + n;
        const int nc = node < N ? node : N - 1;
        const int a = ptr[nc];
        const int b = node < N ? ptr[nc + 1] : a;
        s0[n] = a; len[n] = b - a;
        maxlen = max(maxlen, len[n]);
    }

    float acc[4][8] = {};
    const unsigned int* base = xw + sl * 4;

    if (maxlen > 0) {
        // col index fetch for offset block OFF (edges OFF+g), clamped safe
        #define LOADCOL(dst, OFF)                                            \
            _Pragma("unroll")                                                \
            for (int n = 0; n < 4; ++n) {                                    \
                int idx = (OFF) + g;                                         \
                idx = idx < len[n] ? idx : 0;                                \
                int ei = s0[n] + idx;                                        \
                ei = ei < Emax ? ei : Emax;                                  \
                dst[n] = col[ei];                                            \
            }
        #define GATHER4(dst, c)                                              \
            _Pragma("unroll")                                                \
            for (int n = 0; n < 4; ++n)                                      \
                dst[n] = *(const uintx4*)(base + (size_t)c[n] * 64);
        #define ACCUM4(v, OFF)                                               \
            _Pragma("unroll")                                                \
            for (int n = 0; n < 4; ++n)                                      \
                if ((OFF) + g < len[n]) acc8(acc[n], v[n]);

        int cA[4], cB[4], cC[4], cD[4];
        uintx4 vA[4], vB[4];
        LOADCOL(cA, 0)
        LOADCOL(cB, 4)
        GATHER4(vA, cA)
        LOADCOL(cC, 8)
        GATHER4(vB, cB)
        LOADCOL(cD, 12)

        const int rounds = (maxlen + 7) & ~7;
        for (int off = 0; off < rounds; off += 8) {
            ACCUM4(vA, off)
            GATHER4(vA, cC)            // data for off+8
            LOADCOL(cC, off + 16)
            ACCUM4(vB, off + 4)
            GATHER4(vB, cD)            // data for off+12
            LOADCOL(cD, off + 20)
        }
        #undef LOADCOL
        #undef GATHER4
        #undef ACCUM4
    }

    // ---- LN + ReLU per node, write LDS A-frag tile ----
    #pragma unroll
    for (int n = 0; n < 4; ++n) {
        const int m = wave * 4 + n;
        float a8[8];
        #pragma unroll
        for (int j = 0; j < 8; ++j) {
            float t = acc[n][j];
            t += __shfl_xor(t, 16, 64);
            t += __shfl_xor(t, 32, 64);
            a8[j] = t;
        }
        float s1 = 0.f, s2 = 0.f;
        #pragma unroll
        for (int j = 0; j < 8; ++j) { s1 += a8[j]; s2 += a8[j] * a8[j]; }
        #pragma unroll
        for (int mm = 8; mm >= 1; mm >>= 1) {
            s1 += __shfl_xor(s1, mm, 64);
            s2 += __shfl_xor(s2, mm, 64);
        }
        const float mean = s1 * (1.0f / 128.0f);
        const float var  = s2 * (1.0f / 128.0f) - mean * mean;
        const float inv  = rsqrtf(var + 1e-5f);

        if (g == 0) {
            float o[8];
            #pragma unroll
            for (int j = 0; j < 8; ++j)
                o[j] = fmaxf((a8[j] - mean) * inv, 0.f);
            uintx4 p;
            p.x = (f2bf(o[1]) << 16) | f2bf(o[0]);
            p.y = (f2bf(o[3]) << 16) | f2bf(o[2]);
            p.z = (f2bf(o[5]) << 16) | f2bf(o[4]);
            p.w = (f2bf(o[7]) << 16) | f2bf(o[6]);
            *(uintx4*)(lds + (sl >> 2) * 256 + (sl & 3) * 64 + m * 4) = p;
        }
    }
    __syncthreads();

    // ---- phase 2: 16 x NCOLS_OUT MFMA, wave covers NCOLS_OUT/4 cols --------
    constexpr int WT = NCOLS_OUT / 64;           // tiles per wave (2 or 1)
    const int quad = lane >> 4;
    const int mcol = lane & 15;
    floatx4 macc[WT];
    #pragma unroll
    for (int t = 0; t < WT; ++t) macc[t] = (floatx4){0.f, 0.f, 0.f, 0.f};

    const unsigned int* bbase = Wt + lane * 4;
    #pragma unroll
    for (int s4 = 0; s4 < 4; ++s4) {
        uintx4 ap = *(const uintx4*)(lds + s4 * 256 + lane * 4);
        bf16x8 a = __builtin_bit_cast(bf16x8, ap);
        #pragma unroll
        for (int tt = 0; tt < WT; ++tt) {
            const int t = wave * WT + tt;
            uintx4 bp = *(const uintx4*)(bbase + t * 1024 + s4 * 256);
            bf16x8 b = __builtin_bit_cast(bf16x8, bp);
            macc[tt] = __builtin_amdgcn_mfma_f32_16x16x32_bf16(a, b, macc[tt], 0, 0, 0);
        }
    }

    const int rowStride = NCOLS_OUT >> 1;
    #pragma unroll
    for (int tt = 0; tt < WT; ++tt) {
        const int t = wave * WT + tt;
        #pragma unroll
        for (int r = 0; r < 4; ++r) {
            unsigned int mybf = f2bf(macc[tt][r]);
            unsigned int pair = __shfl_xor(mybf, 1, 64);
            const int orow = tile * 16 + quad * 4 + r;
            if (orow < N && (mcol & 1) == 0) {
                unsigned int packed = (pair << 16) | mybf;
                C[(size_t)orow * rowStride + t * 8 + (mcol >> 1)] = packed;
            }
        }
    }
}

// ---- final: CSR segsum + LN, D=64, fp32 out, no ReLU -----------------------
// Same pipelined 4-nodes-per-wave structure; 16 nodes per block.
__global__ __launch_bounds__(256) void agg_ln64(const unsigned int* __restrict__ xw,
                                                const int* __restrict__ ptr,
                                                const int* __restrict__ col,
                                                float* __restrict__ out,
                                                int N, int Emax) {
    const int tile = blockIdx.x;
    const int wave = threadIdx.x >> 6;
    const int lane = threadIdx.x & 63;
    const int g  = lane >> 4;     // 0..3 edge group
    const int sl = lane & 15;     // 0..15 sublane (owns 4 features)

    int s0[4], len[4];
    int maxlen = 0;
    #pragma unroll
    for (int n = 0; n < 4; ++n) {
        const int node = tile * 16 + wave * 4 + n;
        const int nc = node < N ? node : N - 1;
        const int a = ptr[nc];
        const int b = node < N ? ptr[nc + 1] : a;
        s0[n] = a; len[n] = b - a;
        maxlen = max(maxlen, len[n]);
    }

    float acc[4][4] = {};
    const unsigned int* base = xw + sl * 2;

    if (maxlen > 0) {
        #define LOADCOL(dst, OFF)                                            \
            _Pragma("unroll")                                                \
            for (int n = 0; n < 4; ++n) {                                    \
                int idx = (OFF) + g;                                         \
                idx = idx < len[n] ? idx : 0;                                \
                int ei = s0[n] + idx;                                        \
                ei = ei < Emax ? ei : Emax;                                  \
                dst[n] = col[ei];                                            \
            }
        #define GATHER2(dst, c)                                              \
            _Pragma("unroll")                                                \
            for (int n = 0; n < 4; ++n)                                      \
                dst[n] = *(const uintx2*)(base + (size_t)c[n] * 32);
        #define ACCUM2(v, OFF)                                               \
            _Pragma("unroll")                                                \
            for (int n = 0; n < 4; ++n)                                      \
                if ((OFF) + g < len[n]) acc4(acc[n], v[n]);

        int cA[4], cB[4], cC[4], cD[4];
        uintx2 vA[4], vB[4];
        LOADCOL(cA, 0)
        LOADCOL(cB, 4)
        GATHER2(vA, cA)
        LOADCOL(cC, 8)
        GATHER2(vB, cB)
        LOADCOL(cD, 12)

        const int rounds = (maxlen + 7) & ~7;
        for (int off = 0; off < rounds; off += 8) {
            ACCUM2(vA, off)
            GATHER2(vA, cC)
            LOADCOL(cC, off + 16)
            ACCUM2(vB, off + 4)
            GATHER2(vB, cD)
            LOADCOL(cD, off + 20)
        }
        #undef LOADCOL
        #undef GATHER2
        #undef ACCUM2
    }

    #pragma unroll
    for (int n = 0; n < 4; ++n) {
        const int node = tile * 16 + wave * 4 + n;
        float a4[4];
        #pragma unroll
        for (int j = 0; j < 4; ++j) {
            float t = acc[n][j];
            t += __shfl_xor(t, 16, 64);
            t += __shfl_xor(t, 32, 64);
            a4[j] = t;
        }
        float s1 = 0.f, s2 = 0.f;
        #pragma unroll
        for (int j = 0; j < 4; ++j) { s1 += a4[j]; s2 += a4[j] * a4[j]; }
        #pragma unroll
        for (int mm = 8; mm >= 1; mm >>= 1) {
            s1 += __shfl_xor(s1, mm, 64);
            s2 += __shfl_xor(s2, mm, 64);
        }
        const float mean = s1 * (1.0f / 64.0f);
        const float var  = s2 * (1.0f / 64.0f) - mean * mean;
        const float inv  = rsqrtf(var + 1e-5f);

        if (g == 0 && node < N) {
            float4 o;
            o.x = (a4[0] - mean) * inv;
            o.y = (a4[1] - mean) * inv;
            o.z = (a4[2] - mean) * inv;
            o.w = (a4[3] - mean) * inv;
            *(float4*)(out + (size_t)node * 64 + sl * 4) = o;
        }
    }
}

extern "C" void kernel_launch(void* const* d_in, const int* in_sizes, int n_in,
                              void* d_out, int out_size, void* d_ws, size_t ws_size,
                              hipStream_t stream) {
    const float* feat = (const float*)d_in[0];   // [N,128]
    const float* W0   = (const float*)d_in[1];   // [128,128]
    const float* W1   = (const float*)d_in[2];   // [128,128]
    const float* W2   = (const float*)d_in[3];   // [128,64]
    const int*   ptr  = (const int*)d_in[4];     // [N+1]
    const int*   col  = (const int*)d_in[5];     // [E]
    // d_in[6] = edge_rows, unused (CSR ptr encodes the same segments)

    const int N = in_sizes[4] - 1;               // 50000 (= 3125 * 16)
    const int E = in_sizes[5];                   // 800000
    const int Emax = E - 1;

    unsigned int* buf0 = (unsigned int*)d_ws;                // [N,64] uint, row-major packed
    unsigned int* buf1 = buf0 + (size_t)N * 64;              // [N,64] uint, row-major packed
    unsigned int* WtP  = buf1 + (size_t)N * 64;              // 3 x frag-ordered W
    float*        out  = (float*)d_out;                      // [N,64]

    const int tileBlocks = (N + 15) / 16;        // 3125 (16-node tiles)

    cvt_w<<<48, 256, 0, stream>>>(W0, W1, W2, WtP);

    // Layer 0 GEMM (fp32 feat A-path, in-register convert)
    gemm_mfma<128, true><<<tileBlocks, 64, 0, stream>>>(feat, WtP, buf0, N);
    // Layer 0 agg + LN + ReLU fused with layer 1 GEMM
    agg_gemm<128><<<tileBlocks, 256, 0, stream>>>(buf0, ptr, col, WtP + 128 * 64, buf1, N, Emax);
    // Layer 1 agg + LN + ReLU fused with layer 2 GEMM (D_out=64)
    agg_gemm<64><<<tileBlocks, 256, 0, stream>>>(buf1, ptr, col, WtP + 2 * 128 * 64, buf0, N, Emax);
    // Layer 2 agg + LN (no ReLU), fp32 out
    agg_ln64<<<tileBlocks, 256, 0, stream>>>(buf0, ptr, col, out, N, Emax);
}